// Round 2
// baseline (335.849 us; speedup 1.0000x reference)
//
#include <hip/hip_runtime.h>
#include <math.h>

// ---------------------------------------------------------------------------
// AmplitudeQuantumNet: conv1+bn+relu+pool -> conv2+bn+relu+pool -> fc+tanh ->
// 8-qubit statevector sim (H layer, 10x [RX x8 + S/T phase + CZ diag]) ->
// expvals -> 8->128->64->10 MLP head.  All fp32.
// ---------------------------------------------------------------------------

#define B_SZ 1024

// workspace offsets (in floats)
#define OFF_FCWP   0            // [3136][256] permuted fc_w
#define OFF_W2T    802816       // [288][64]   conv2 w transposed (k-major)
#define OFF_W1T    821248       // [9][32]     conv1 w transposed
#define OFF_SC1    821536       // [32]
#define OFF_SH1    821568       // [32]
#define OFF_SC2    821600      // [64]
#define OFF_SH2    821664      // [64]
#define OFF_H1     821728      // [1024][32][14][14]
#define OFF_H2P    7244256     // [1024][49][64]  (spatial-major, oc inner)
#define OFF_FEATS  10455520    // [1024][256]
// total = 10717664 floats = 42.9 MB

__constant__ float C_COS8[8] = {1.f, 0.70710678f, 0.f, -0.70710678f, -1.f, -0.70710678f, 0.f, 0.70710678f};
__constant__ float C_SIN8[8] = {0.f, 0.70710678f, 1.f, 0.70710678f, 0.f, -0.70710678f, -1.f, -0.70710678f};

// ------------------------- prep: transposes + bn folding -------------------
__global__ __launch_bounds__(256) void prep_kernel(
    const float* __restrict__ fc_w, const float* __restrict__ c2w, const float* __restrict__ c1w,
    const float* __restrict__ bn1g, const float* __restrict__ bn1b, const float* __restrict__ bn1m,
    const float* __restrict__ bn1v, const float* __restrict__ c1b,
    const float* __restrict__ bn2g, const float* __restrict__ bn2b, const float* __restrict__ bn2m,
    const float* __restrict__ bn2v, const float* __restrict__ c2b,
    float* __restrict__ ws) {
  int g = blockIdx.x * 256 + threadIdx.x;   // < 802816
  // fc_w permutation: k' = s*64 + oc  <->  original col = oc*49 + s
  int kp = g >> 8;          // [0,3136)
  int o  = g & 255;
  int s  = kp >> 6;         // [0,49)
  int oc = kp & 63;
  ws[OFF_FCWP + kp * 256 + o] = fc_w[o * 3136 + oc * 49 + s];

  if (g < 18432) {          // w2T[k2*64+oc] = c2w[oc*288+k2]
    ws[OFF_W2T + g] = c2w[(g & 63) * 288 + (g >> 6)];
  }
  if (g < 288) {            // w1T[k*32+oc] = c1w[oc*9+k]
    ws[OFF_W1T + g] = c1w[(g & 31) * 9 + (g >> 5)];
  }
  if (g < 32) {
    float inv = bn1g[g] / sqrtf(bn1v[g] + 1e-5f);
    ws[OFF_SC1 + g] = inv;
    ws[OFF_SH1 + g] = c1b[g] * inv + bn1b[g] - bn1m[g] * inv;
  }
  if (g < 64) {
    float inv = bn2g[g] / sqrtf(bn2v[g] + 1e-5f);
    ws[OFF_SC2 + g] = inv;
    ws[OFF_SH2 + g] = c2b[g] * inv + bn2b[g] - bn2m[g] * inv;
  }
}

// ------------------------- conv1 + bn + relu + pool ------------------------
// in: x[b][28][28], out: h1[b][32][14][14] (NCHW)
__global__ __launch_bounds__(256) void conv1_kernel(
    const float* __restrict__ x, const float* __restrict__ w1T,
    const float* __restrict__ sc1, const float* __restrict__ sh1,
    float* __restrict__ h1) {
  const int b = blockIdx.x, tid = threadIdx.x;
  __shared__ float xs[30][32];     // padded 28x28, row stride 32
  __shared__ float w1s[288];
  __shared__ float sc1s[32], sh1s[32];

  float4* xsf = (float4*)&xs[0][0];
  if (tid < 240) xsf[tid] = make_float4(0.f, 0.f, 0.f, 0.f);
  __syncthreads();
  const float* xb = x + b * 784;
  for (int i = tid; i < 784; i += 256) {
    int y = i / 28, c = i - y * 28;
    xs[y + 1][c + 1] = xb[i];
  }
  for (int i = tid; i < 288; i += 256) w1s[i] = w1T[i];   // FIX: was `if (tid<288)` with 256 threads
  if (tid < 32) { sc1s[tid] = sc1[tid]; sh1s[tid] = sh1[tid]; }
  __syncthreads();

  for (int t = tid; t < 448; t += 256) {
    const int oc = t & 31, py = t >> 5;       // wave-uniform-ish py
    float wv[9];
#pragma unroll
    for (int k = 0; k < 9; ++k) wv[k] = w1s[k * 32 + oc];
    float acc0[28], acc1[28];
#pragma unroll
    for (int j = 0; j < 28; ++j) { acc0[j] = 0.f; acc1[j] = 0.f; }
#pragma unroll
    for (int r = 0; r < 4; ++r) {
      const int pr = 2 * py + r;
      float row[32];
#pragma unroll
      for (int q = 0; q < 8; ++q) {
        float4 v = *(const float4*)&xs[pr][4 * q];
        row[4 * q] = v.x; row[4 * q + 1] = v.y; row[4 * q + 2] = v.z; row[4 * q + 3] = v.w;
      }
      if (r <= 2) {
#pragma unroll
        for (int kx = 0; kx < 3; ++kx) {
          const float w = wv[r * 3 + kx];
#pragma unroll
          for (int xx = 0; xx < 28; ++xx) acc0[xx] = fmaf(row[xx + kx], w, acc0[xx]);
        }
      }
      if (r >= 1) {
#pragma unroll
        for (int kx = 0; kx < 3; ++kx) {
          const float w = wv[(r - 1) * 3 + kx];
#pragma unroll
          for (int xx = 0; xx < 28; ++xx) acc1[xx] = fmaf(row[xx + kx], w, acc1[xx]);
        }
      }
    }
    const float sc = sc1s[oc], sh = sh1s[oc];
    float* dst = h1 + b * 6272 + oc * 196 + py * 14;
#pragma unroll
    for (int px = 0; px < 14; ++px) {
      float v0 = fmaxf(fmaf(acc0[2 * px], sc, sh), 0.f);
      float v1 = fmaxf(fmaf(acc0[2 * px + 1], sc, sh), 0.f);
      float v2 = fmaxf(fmaf(acc1[2 * px], sc, sh), 0.f);
      float v3 = fmaxf(fmaf(acc1[2 * px + 1], sc, sh), 0.f);
      dst[px] = fmaxf(fmaxf(v0, v1), fmaxf(v2, v3));
    }
  }
}

// ------------------------- conv2 + bn + relu + pool ------------------------
// in: h1[b][32][14][14], out: h2p[b][49][64] (spatial-major, oc inner)
__global__ __launch_bounds__(256) void conv2_kernel(
    const float* __restrict__ h1, const float* __restrict__ w2T,
    const float* __restrict__ sc2, const float* __restrict__ sh2,
    float* __restrict__ h2p) {
  const int b = blockIdx.x, tid = threadIdx.x;
  __shared__ float ins[32][16][16];   // 32 KB padded input
  float4* insf = (float4*)&ins[0][0][0];
#pragma unroll
  for (int q = 0; q < 8; ++q) insf[tid + 256 * q] = make_float4(0.f, 0.f, 0.f, 0.f);
  __syncthreads();
  const float4* src = (const float4*)(h1 + b * 6272);
  for (int i = tid; i < 1568; i += 256) {
    float4 v = src[i];
    float vv[4] = {v.x, v.y, v.z, v.w};
    int e = 4 * i;
#pragma unroll
    for (int j = 0; j < 4; ++j) {
      int ee = e + j;
      int ic = ee / 196; int rem = ee - ic * 196;
      int r = rem / 14;  int c = rem - r * 14;
      ins[ic][r + 1][c + 1] = vv[j];
    }
  }
  __syncthreads();

  for (int t = tid; t < 448; t += 256) {
    const int oc = t & 63, py = t >> 6;   // py uniform across each wave
    float acc0[14], acc1[14];
#pragma unroll
    for (int j = 0; j < 14; ++j) { acc0[j] = 0.f; acc1[j] = 0.f; }
    for (int ic = 0; ic < 32; ++ic) {
      float wv[9];
#pragma unroll
      for (int k = 0; k < 9; ++k) wv[k] = w2T[(ic * 9 + k) * 64 + oc];  // coalesced across wave
#pragma unroll
      for (int r = 0; r < 4; ++r) {
        const int pr = 2 * py + r;
        float row[16];
#pragma unroll
        for (int q = 0; q < 4; ++q) {
          float4 v = *(const float4*)&ins[ic][pr][4 * q];   // wave-broadcast
          row[4 * q] = v.x; row[4 * q + 1] = v.y; row[4 * q + 2] = v.z; row[4 * q + 3] = v.w;
        }
        if (r <= 2) {
#pragma unroll
          for (int kx = 0; kx < 3; ++kx) {
            const float w = wv[r * 3 + kx];
#pragma unroll
            for (int xx = 0; xx < 14; ++xx) acc0[xx] = fmaf(row[xx + kx], w, acc0[xx]);
          }
        }
        if (r >= 1) {
#pragma unroll
          for (int kx = 0; kx < 3; ++kx) {
            const float w = wv[(r - 1) * 3 + kx];
#pragma unroll
            for (int xx = 0; xx < 14; ++xx) acc1[xx] = fmaf(row[xx + kx], w, acc1[xx]);
          }
        }
      }
    }
    const float sc = sc2[oc], sh = sh2[oc];
    float* dst = h2p + b * 3136 + oc;
#pragma unroll
    for (int px = 0; px < 7; ++px) {
      float v0 = fmaxf(fmaf(acc0[2 * px], sc, sh), 0.f);
      float v1 = fmaxf(fmaf(acc0[2 * px + 1], sc, sh), 0.f);
      float v2 = fmaxf(fmaf(acc1[2 * px], sc, sh), 0.f);
      float v3 = fmaxf(fmaf(acc1[2 * px + 1], sc, sh), 0.f);
      dst[(py * 7 + px) * 64] = fmaxf(fmaxf(v0, v1), fmaxf(v2, v3));   // coalesced across wave
    }
  }
}

// ------------------------- fc + tanh ---------------------------------------
// C[1024][256] = tanh(A[1024][3136] @ Bp[3136][256] + bias)
__global__ __launch_bounds__(256) void fc_kernel(
    const float* __restrict__ A, const float* __restrict__ Bp,
    const float* __restrict__ bias, float* __restrict__ C) {
  __shared__ float As[32][34];   // [k][m], transposed
  __shared__ float Bs[32][68];   // [k][n]
  const int tid = threadIdx.x;
  const int m0 = blockIdx.y * 32, n0 = blockIdx.x * 64;
  const int am = tid >> 3, ak4 = tid & 7;
  const int bn4 = tid & 15, bk = tid >> 4;
  const int tx = tid & 15, ty = tid >> 4;
  float acc[2][4] = {{0.f, 0.f, 0.f, 0.f}, {0.f, 0.f, 0.f, 0.f}};
  for (int k0 = 0; k0 < 3136; k0 += 32) {
    float4 av  = *(const float4*)&A[(m0 + am) * 3136 + k0 + 4 * ak4];
    float4 bv0 = *(const float4*)&Bp[(k0 + bk) * 256 + n0 + 4 * bn4];
    float4 bv1 = *(const float4*)&Bp[(k0 + bk + 16) * 256 + n0 + 4 * bn4];
    As[4 * ak4 + 0][am] = av.x; As[4 * ak4 + 1][am] = av.y;
    As[4 * ak4 + 2][am] = av.z; As[4 * ak4 + 3][am] = av.w;
    *(float4*)&Bs[bk][4 * bn4] = bv0;
    *(float4*)&Bs[bk + 16][4 * bn4] = bv1;
    __syncthreads();
#pragma unroll
    for (int kk = 0; kk < 32; ++kk) {
      float2 a2 = *(const float2*)&As[kk][2 * ty];
      float4 b4 = *(const float4*)&Bs[kk][4 * tx];
      acc[0][0] = fmaf(a2.x, b4.x, acc[0][0]); acc[0][1] = fmaf(a2.x, b4.y, acc[0][1]);
      acc[0][2] = fmaf(a2.x, b4.z, acc[0][2]); acc[0][3] = fmaf(a2.x, b4.w, acc[0][3]);
      acc[1][0] = fmaf(a2.y, b4.x, acc[1][0]); acc[1][1] = fmaf(a2.y, b4.y, acc[1][1]);
      acc[1][2] = fmaf(a2.y, b4.z, acc[1][2]); acc[1][3] = fmaf(a2.y, b4.w, acc[1][3]);
    }
    __syncthreads();
  }
  float4 bb = *(const float4*)&bias[n0 + 4 * tx];
#pragma unroll
  for (int i = 0; i < 2; ++i) {
    const int m = m0 + 2 * ty + i;
    float4 o;
    o.x = tanhf(acc[i][0] + bb.x); o.y = tanhf(acc[i][1] + bb.y);
    o.z = tanhf(acc[i][2] + bb.z); o.w = tanhf(acc[i][3] + bb.w);
    *(float4*)&C[m * 256 + n0 + 4 * tx] = o;
  }
}

// ------------------------- quantum sim + MLP head --------------------------
__global__ __launch_bounds__(256) void quantum_kernel(
    const float* __restrict__ feats, const float* __restrict__ qp,
    const float* __restrict__ p1w, const float* __restrict__ p1b,
    const float* __restrict__ p2w, const float* __restrict__ p2b,
    const float* __restrict__ p3w, const float* __restrict__ p3b,
    float* __restrict__ out) {
  const int b = blockIdx.x, tid = threadIdx.x;
  __shared__ float2 buf[2][256];
  __shared__ float csl[160];       // cos/sin of q_params/2
  __shared__ float part[4][8];
  __shared__ float qv[8];
  __shared__ float z1[128];
  __shared__ float z2s[64];

  if (tid < 80) {
    float t = 0.5f * qp[tid];
    csl[2 * tid] = cosf(t);
    csl[2 * tid + 1] = sinf(t);
  }

  float f = feats[b * 256 + tid];
  float ss = f * f;
#pragma unroll
  for (int off = 32; off >= 1; off >>= 1) ss += __shfl_xor(ss, off);
  const int lane = tid & 63, wid = tid >> 6;
  if (lane == 0) part[wid][0] = ss;
  __syncthreads();
  const float tot = part[0][0] + part[1][0] + part[2][0] + part[3][0];
  const float inv = 1.0f / sqrtf(tot);
  float re = f * inv, im = 0.f;

  // fixed diagonal for this basis state: S/T phases (even/odd wires) * CZ signs
  const int k8 = (2 * __popc(tid & 0xAA) + __popc(tid & 0x55)) & 7;
  float dre = C_COS8[k8], dim_ = C_SIN8[k8];
  {
    const int i = tid;
    int par = ((i >> 7) & (i >> 6)) ^ ((i >> 5) & (i >> 4)) ^ ((i >> 3) & (i >> 2)) ^ ((i >> 1) & i)
            ^ ((i >> 6) & (i >> 5)) ^ ((i >> 4) & (i >> 3)) ^ ((i >> 2) & (i >> 1));
    if (par & 1) { dre = -dre; dim_ = -dim_; }
  }

  int cur = 0;
  buf[0][tid] = make_float2(re, im);
  __syncthreads();

  // Hadamard layer (wire w <-> bit (7-w))
#pragma unroll
  for (int w = 0; w < 8; ++w) {
    const int m = 1 << (7 - w);
    float2 p = buf[cur][tid ^ m];
    const float RS = 0.70710678118654752f;
    float nre, nim;
    if (tid & m) { nre = (p.x - re) * RS; nim = (p.y - im) * RS; }
    else         { nre = (re + p.x) * RS; nim = (im + p.y) * RS; }
    cur ^= 1; re = nre; im = nim;
    buf[cur][tid] = make_float2(re, im);
    __syncthreads();
  }

  // 10 layers: 8 RX gates + diagonal (folded into wire-7 write)
  for (int layer = 0; layer < 10; ++layer) {
#pragma unroll
    for (int w = 0; w < 8; ++w) {
      const int m = 1 << (7 - w);
      const int g = layer * 8 + w;
      const float c = csl[2 * g], s = csl[2 * g + 1];
      float2 p = buf[cur][tid ^ m];
      float nre = fmaf(s, p.y, c * re);     // c*a - i*s*b
      float nim = fmaf(-s, p.x, c * im);
      if (w == 7) {
        float tre = nre * dre - nim * dim_;
        nim = fmaf(nre, dim_, nim * dre);
        nre = tre;
      }
      cur ^= 1; re = nre; im = nim;
      buf[cur][tid] = make_float2(re, im);
      __syncthreads();
    }
  }

  // expvals of PauliZ on each wire
  const float prb = re * re + im * im;
#pragma unroll
  for (int w = 0; w < 8; ++w) {
    float v = ((tid >> (7 - w)) & 1) ? -prb : prb;
#pragma unroll
    for (int off = 32; off >= 1; off >>= 1) v += __shfl_xor(v, off);
    if (lane == 0) part[wid][w] = v;
  }
  __syncthreads();
  if (tid < 8) qv[tid] = part[0][tid] + part[1][tid] + part[2][tid] + part[3][tid];
  __syncthreads();

  // head: 8 -> 128 -> 64 -> 10
  if (tid < 128) {
    float a = p1b[tid];
#pragma unroll
    for (int k = 0; k < 8; ++k) a = fmaf(qv[k], p1w[tid * 8 + k], a);
    z1[tid] = fmaxf(a, 0.f);
  }
  __syncthreads();
  if (tid < 64) {
    float a = p2b[tid];
    for (int k = 0; k < 128; ++k) a = fmaf(z1[k], p2w[tid * 128 + k], a);
    z2s[tid] = fmaxf(a, 0.f);
  }
  __syncthreads();
  if (tid < 10) {
    float a = p3b[tid];
    for (int k = 0; k < 64; ++k) a = fmaf(z2s[k], p3w[tid * 64 + k], a);
    out[b * 10 + tid] = a;
  }
}

// ---------------------------------------------------------------------------
extern "C" void kernel_launch(void* const* d_in, const int* in_sizes, int n_in,
                              void* d_out, int out_size, void* d_ws, size_t ws_size,
                              hipStream_t stream) {
  (void)in_sizes; (void)n_in; (void)out_size; (void)ws_size;
  const float* x    = (const float*)d_in[0];
  const float* c1w  = (const float*)d_in[1];
  const float* c1b  = (const float*)d_in[2];
  const float* bn1g = (const float*)d_in[3];
  const float* bn1b = (const float*)d_in[4];
  const float* bn1m = (const float*)d_in[5];
  const float* bn1v = (const float*)d_in[6];
  const float* c2w  = (const float*)d_in[7];
  const float* c2b  = (const float*)d_in[8];
  const float* bn2g = (const float*)d_in[9];
  const float* bn2b = (const float*)d_in[10];
  const float* bn2m = (const float*)d_in[11];
  const float* bn2v = (const float*)d_in[12];
  const float* fc_w = (const float*)d_in[13];
  const float* fc_b = (const float*)d_in[14];
  const float* qp   = (const float*)d_in[15];
  const float* p1w  = (const float*)d_in[16];
  const float* p1b  = (const float*)d_in[17];
  const float* p2w  = (const float*)d_in[18];
  const float* p2b  = (const float*)d_in[19];
  const float* p3w  = (const float*)d_in[20];
  const float* p3b  = (const float*)d_in[21];
  float* ws = (float*)d_ws;
  float* outp = (float*)d_out;

  prep_kernel<<<3136, 256, 0, stream>>>(fc_w, c2w, c1w,
                                        bn1g, bn1b, bn1m, bn1v, c1b,
                                        bn2g, bn2b, bn2m, bn2v, c2b, ws);
  conv1_kernel<<<B_SZ, 256, 0, stream>>>(x, ws + OFF_W1T, ws + OFF_SC1, ws + OFF_SH1, ws + OFF_H1);
  conv2_kernel<<<B_SZ, 256, 0, stream>>>(ws + OFF_H1, ws + OFF_W2T, ws + OFF_SC2, ws + OFF_SH2, ws + OFF_H2P);
  fc_kernel<<<dim3(4, 32), 256, 0, stream>>>(ws + OFF_H2P, ws + OFF_FCWP, fc_b, ws + OFF_FEATS);
  quantum_kernel<<<B_SZ, 256, 0, stream>>>(ws + OFF_FEATS, qp, p1w, p1b, p2w, p2b, p3w, p3b, outp);
}

// Round 3
// 266.502 us; speedup vs baseline: 1.2602x; 1.2602x over previous
//
#include <hip/hip_runtime.h>
#include <math.h>

// ---------------------------------------------------------------------------
// AmplitudeQuantumNet: conv1+bn+relu+pool -> conv2+bn+relu+pool -> fc+tanh ->
// 8-qubit statevector sim (H layer, 10x [RX x8 + S/T phase + CZ diag]) ->
// expvals -> 8->128->64->10 MLP head.  All fp32.
// R2: fc split-K x7 (occupancy fix: 128 -> 896 blocks), partial-reduce+tanh
//     folded into quantum kernel; quantum uses __shfl_xor for wires 2-7
//     (barriers 88 -> 22).
// ---------------------------------------------------------------------------

#define B_SZ 1024

// workspace offsets (in floats)
#define OFF_FCWP   0            // [3136][256] permuted fc_w
#define OFF_W2T    802816       // [288][64]   conv2 w transposed (k-major)
#define OFF_W1T    821248       // [9][32]     conv1 w transposed
#define OFF_SC1    821536       // [32]
#define OFF_SH1    821568       // [32]
#define OFF_SC2    821600      // [64]
#define OFF_SH2    821664      // [64]
#define OFF_H1     821728      // [1024][32][14][14]; reused as fc partials [7][1024][256]
#define OFF_H2P    7244256     // [1024][49][64]  (spatial-major, oc inner)
// total < 10.5M floats

#define KSPLIT 7
#define KCHUNK 448              // 3136 / 7, = 14 * 32

__constant__ float C_COS8[8] = {1.f, 0.70710678f, 0.f, -0.70710678f, -1.f, -0.70710678f, 0.f, 0.70710678f};
__constant__ float C_SIN8[8] = {0.f, 0.70710678f, 1.f, 0.70710678f, 0.f, -0.70710678f, -1.f, -0.70710678f};

// ------------------------- prep: transposes + bn folding -------------------
__global__ __launch_bounds__(256) void prep_kernel(
    const float* __restrict__ fc_w, const float* __restrict__ c2w, const float* __restrict__ c1w,
    const float* __restrict__ bn1g, const float* __restrict__ bn1b, const float* __restrict__ bn1m,
    const float* __restrict__ bn1v, const float* __restrict__ c1b,
    const float* __restrict__ bn2g, const float* __restrict__ bn2b, const float* __restrict__ bn2m,
    const float* __restrict__ bn2v, const float* __restrict__ c2b,
    float* __restrict__ ws) {
  int g = blockIdx.x * 256 + threadIdx.x;   // < 802816
  // fc_w permutation: k' = s*64 + oc  <->  original col = oc*49 + s
  int kp = g >> 8;          // [0,3136)
  int o  = g & 255;
  int s  = kp >> 6;         // [0,49)
  int oc = kp & 63;
  ws[OFF_FCWP + kp * 256 + o] = fc_w[o * 3136 + oc * 49 + s];

  if (g < 18432) {          // w2T[k2*64+oc] = c2w[oc*288+k2]
    ws[OFF_W2T + g] = c2w[(g & 63) * 288 + (g >> 6)];
  }
  if (g < 288) {            // w1T[k*32+oc] = c1w[oc*9+k]
    ws[OFF_W1T + g] = c1w[(g & 31) * 9 + (g >> 5)];
  }
  if (g < 32) {
    float inv = bn1g[g] / sqrtf(bn1v[g] + 1e-5f);
    ws[OFF_SC1 + g] = inv;
    ws[OFF_SH1 + g] = c1b[g] * inv + bn1b[g] - bn1m[g] * inv;
  }
  if (g < 64) {
    float inv = bn2g[g] / sqrtf(bn2v[g] + 1e-5f);
    ws[OFF_SC2 + g] = inv;
    ws[OFF_SH2 + g] = c2b[g] * inv + bn2b[g] - bn2m[g] * inv;
  }
}

// ------------------------- conv1 + bn + relu + pool ------------------------
// in: x[b][28][28], out: h1[b][32][14][14] (NCHW)
__global__ __launch_bounds__(256) void conv1_kernel(
    const float* __restrict__ x, const float* __restrict__ w1T,
    const float* __restrict__ sc1, const float* __restrict__ sh1,
    float* __restrict__ h1) {
  const int b = blockIdx.x, tid = threadIdx.x;
  __shared__ float xs[30][32];     // padded 28x28, row stride 32
  __shared__ float w1s[288];
  __shared__ float sc1s[32], sh1s[32];

  float4* xsf = (float4*)&xs[0][0];
  if (tid < 240) xsf[tid] = make_float4(0.f, 0.f, 0.f, 0.f);
  __syncthreads();
  const float* xb = x + b * 784;
  for (int i = tid; i < 784; i += 256) {
    int y = i / 28, c = i - y * 28;
    xs[y + 1][c + 1] = xb[i];
  }
  for (int i = tid; i < 288; i += 256) w1s[i] = w1T[i];
  if (tid < 32) { sc1s[tid] = sc1[tid]; sh1s[tid] = sh1[tid]; }
  __syncthreads();

  for (int t = tid; t < 448; t += 256) {
    const int oc = t & 31, py = t >> 5;
    float wv[9];
#pragma unroll
    for (int k = 0; k < 9; ++k) wv[k] = w1s[k * 32 + oc];
    float acc0[28], acc1[28];
#pragma unroll
    for (int j = 0; j < 28; ++j) { acc0[j] = 0.f; acc1[j] = 0.f; }
#pragma unroll
    for (int r = 0; r < 4; ++r) {
      const int pr = 2 * py + r;
      float row[32];
#pragma unroll
      for (int q = 0; q < 8; ++q) {
        float4 v = *(const float4*)&xs[pr][4 * q];
        row[4 * q] = v.x; row[4 * q + 1] = v.y; row[4 * q + 2] = v.z; row[4 * q + 3] = v.w;
      }
      if (r <= 2) {
#pragma unroll
        for (int kx = 0; kx < 3; ++kx) {
          const float w = wv[r * 3 + kx];
#pragma unroll
          for (int xx = 0; xx < 28; ++xx) acc0[xx] = fmaf(row[xx + kx], w, acc0[xx]);
        }
      }
      if (r >= 1) {
#pragma unroll
        for (int kx = 0; kx < 3; ++kx) {
          const float w = wv[(r - 1) * 3 + kx];
#pragma unroll
          for (int xx = 0; xx < 28; ++xx) acc1[xx] = fmaf(row[xx + kx], w, acc1[xx]);
        }
      }
    }
    const float sc = sc1s[oc], sh = sh1s[oc];
    float* dst = h1 + b * 6272 + oc * 196 + py * 14;
#pragma unroll
    for (int px = 0; px < 14; ++px) {
      float v0 = fmaxf(fmaf(acc0[2 * px], sc, sh), 0.f);
      float v1 = fmaxf(fmaf(acc0[2 * px + 1], sc, sh), 0.f);
      float v2 = fmaxf(fmaf(acc1[2 * px], sc, sh), 0.f);
      float v3 = fmaxf(fmaf(acc1[2 * px + 1], sc, sh), 0.f);
      dst[px] = fmaxf(fmaxf(v0, v1), fmaxf(v2, v3));
    }
  }
}

// ------------------------- conv2 + bn + relu + pool ------------------------
// in: h1[b][32][14][14], out: h2p[b][49][64] (spatial-major, oc inner)
__global__ __launch_bounds__(256) void conv2_kernel(
    const float* __restrict__ h1, const float* __restrict__ w2T,
    const float* __restrict__ sc2, const float* __restrict__ sh2,
    float* __restrict__ h2p) {
  const int b = blockIdx.x, tid = threadIdx.x;
  __shared__ float ins[32][16][16];   // 32 KB padded input
  float4* insf = (float4*)&ins[0][0][0];
#pragma unroll
  for (int q = 0; q < 8; ++q) insf[tid + 256 * q] = make_float4(0.f, 0.f, 0.f, 0.f);
  __syncthreads();
  const float4* src = (const float4*)(h1 + b * 6272);
  for (int i = tid; i < 1568; i += 256) {
    float4 v = src[i];
    float vv[4] = {v.x, v.y, v.z, v.w};
    int e = 4 * i;
#pragma unroll
    for (int j = 0; j < 4; ++j) {
      int ee = e + j;
      int ic = ee / 196; int rem = ee - ic * 196;
      int r = rem / 14;  int c = rem - r * 14;
      ins[ic][r + 1][c + 1] = vv[j];
    }
  }
  __syncthreads();

  for (int t = tid; t < 448; t += 256) {
    const int oc = t & 63, py = t >> 6;   // py uniform across each wave
    float acc0[14], acc1[14];
#pragma unroll
    for (int j = 0; j < 14; ++j) { acc0[j] = 0.f; acc1[j] = 0.f; }
    for (int ic = 0; ic < 32; ++ic) {
      float wv[9];
#pragma unroll
      for (int k = 0; k < 9; ++k) wv[k] = w2T[(ic * 9 + k) * 64 + oc];  // coalesced across wave
#pragma unroll
      for (int r = 0; r < 4; ++r) {
        const int pr = 2 * py + r;
        float row[16];
#pragma unroll
        for (int q = 0; q < 4; ++q) {
          float4 v = *(const float4*)&ins[ic][pr][4 * q];   // wave-broadcast
          row[4 * q] = v.x; row[4 * q + 1] = v.y; row[4 * q + 2] = v.z; row[4 * q + 3] = v.w;
        }
        if (r <= 2) {
#pragma unroll
          for (int kx = 0; kx < 3; ++kx) {
            const float w = wv[r * 3 + kx];
#pragma unroll
            for (int xx = 0; xx < 14; ++xx) acc0[xx] = fmaf(row[xx + kx], w, acc0[xx]);
          }
        }
        if (r >= 1) {
#pragma unroll
          for (int kx = 0; kx < 3; ++kx) {
            const float w = wv[(r - 1) * 3 + kx];
#pragma unroll
            for (int xx = 0; xx < 14; ++xx) acc1[xx] = fmaf(row[xx + kx], w, acc1[xx]);
          }
        }
      }
    }
    const float sc = sc2[oc], sh = sh2[oc];
    float* dst = h2p + b * 3136 + oc;
#pragma unroll
    for (int px = 0; px < 7; ++px) {
      float v0 = fmaxf(fmaf(acc0[2 * px], sc, sh), 0.f);
      float v1 = fmaxf(fmaf(acc0[2 * px + 1], sc, sh), 0.f);
      float v2 = fmaxf(fmaf(acc1[2 * px], sc, sh), 0.f);
      float v3 = fmaxf(fmaf(acc1[2 * px + 1], sc, sh), 0.f);
      dst[(py * 7 + px) * 64] = fmaxf(fmaxf(v0, v1), fmaxf(v2, v3));   // coalesced across wave
    }
  }
}

// ------------------------- fc (split-K partials) ----------------------------
// Part[z][1024][256] += A[1024][kz] @ Bp[kz][256] for k-slice z
__global__ __launch_bounds__(256) void fc_kernel(
    const float* __restrict__ A, const float* __restrict__ Bp,
    float* __restrict__ Part) {
  __shared__ float As[32][34];   // [k][m], transposed
  __shared__ float Bs[32][68];   // [k][n]
  const int tid = threadIdx.x;
  const int m0 = blockIdx.y * 32, n0 = blockIdx.x * 64;
  const int kbase = blockIdx.z * KCHUNK;
  const int am = tid >> 3, ak4 = tid & 7;
  const int bn4 = tid & 15, bk = tid >> 4;
  const int tx = tid & 15, ty = tid >> 4;
  float acc[2][4] = {{0.f, 0.f, 0.f, 0.f}, {0.f, 0.f, 0.f, 0.f}};
  for (int k0 = kbase; k0 < kbase + KCHUNK; k0 += 32) {
    float4 av  = *(const float4*)&A[(m0 + am) * 3136 + k0 + 4 * ak4];
    float4 bv0 = *(const float4*)&Bp[(k0 + bk) * 256 + n0 + 4 * bn4];
    float4 bv1 = *(const float4*)&Bp[(k0 + bk + 16) * 256 + n0 + 4 * bn4];
    As[4 * ak4 + 0][am] = av.x; As[4 * ak4 + 1][am] = av.y;
    As[4 * ak4 + 2][am] = av.z; As[4 * ak4 + 3][am] = av.w;
    *(float4*)&Bs[bk][4 * bn4] = bv0;
    *(float4*)&Bs[bk + 16][4 * bn4] = bv1;
    __syncthreads();
#pragma unroll
    for (int kk = 0; kk < 32; ++kk) {
      float2 a2 = *(const float2*)&As[kk][2 * ty];
      float4 b4 = *(const float4*)&Bs[kk][4 * tx];
      acc[0][0] = fmaf(a2.x, b4.x, acc[0][0]); acc[0][1] = fmaf(a2.x, b4.y, acc[0][1]);
      acc[0][2] = fmaf(a2.x, b4.z, acc[0][2]); acc[0][3] = fmaf(a2.x, b4.w, acc[0][3]);
      acc[1][0] = fmaf(a2.y, b4.x, acc[1][0]); acc[1][1] = fmaf(a2.y, b4.y, acc[1][1]);
      acc[1][2] = fmaf(a2.y, b4.z, acc[1][2]); acc[1][3] = fmaf(a2.y, b4.w, acc[1][3]);
    }
    __syncthreads();
  }
  float* dst = Part + blockIdx.z * 262144;
#pragma unroll
  for (int i = 0; i < 2; ++i) {
    const int m = m0 + 2 * ty + i;
    *(float4*)&dst[m * 256 + n0 + 4 * tx] =
        make_float4(acc[i][0], acc[i][1], acc[i][2], acc[i][3]);
  }
}

// ------------------------- quantum sim + MLP head --------------------------
// feats = tanh(sum_z Part[z][b][tid] + fc_b[tid]) computed inline.
__global__ __launch_bounds__(256) void quantum_kernel(
    const float* __restrict__ Part, const float* __restrict__ fc_b,
    const float* __restrict__ qp,
    const float* __restrict__ p1w, const float* __restrict__ p1b,
    const float* __restrict__ p2w, const float* __restrict__ p2b,
    const float* __restrict__ p3w, const float* __restrict__ p3b,
    float* __restrict__ out) {
  const int b = blockIdx.x, tid = threadIdx.x;
  __shared__ float2 buf[2][256];
  __shared__ float csl[160];       // cos/sin of q_params/2
  __shared__ float part[4][8];
  __shared__ float qv[8];
  __shared__ float z1[128];
  __shared__ float z2s[64];

  if (tid < 80) {
    float t = 0.5f * qp[tid];
    csl[2 * tid] = cosf(t);
    csl[2 * tid + 1] = sinf(t);
  }

  // fc partial-sum + bias + tanh (split-K reduce folded in)
  float f = fc_b[tid];
#pragma unroll
  for (int z = 0; z < KSPLIT; ++z) f += Part[z * 262144 + b * 256 + tid];
  f = tanhf(f);

  float ss = f * f;
#pragma unroll
  for (int off = 32; off >= 1; off >>= 1) ss += __shfl_xor(ss, off);
  const int lane = tid & 63, wid = tid >> 6;
  if (lane == 0) part[wid][0] = ss;
  __syncthreads();
  const float tot = part[0][0] + part[1][0] + part[2][0] + part[3][0];
  const float inv = 1.0f / sqrtf(tot);
  float re = f * inv, im = 0.f;

  // fixed diagonal for this basis state: S/T phases (even/odd wires) * CZ signs
  const int k8 = (2 * __popc(tid & 0xAA) + __popc(tid & 0x55)) & 7;
  float dre = C_COS8[k8], dim_ = C_SIN8[k8];
  {
    const int i = tid;
    int par = ((i >> 7) & (i >> 6)) ^ ((i >> 5) & (i >> 4)) ^ ((i >> 3) & (i >> 2)) ^ ((i >> 1) & i)
            ^ ((i >> 6) & (i >> 5)) ^ ((i >> 4) & (i >> 3)) ^ ((i >> 2) & (i >> 1));
    if (par & 1) { dre = -dre; dim_ = -dim_; }
  }

  int cur = 0;
  const float RS = 0.70710678118654752f;

  // Hadamard layer: wires 0,1 (m=128,64) cross-wave via LDS; wires 2-7 shuffles
#pragma unroll
  for (int w = 0; w < 2; ++w) {
    const int m = 128 >> w;
    cur ^= 1;
    buf[cur][tid] = make_float2(re, im);
    __syncthreads();
    float2 p = buf[cur][tid ^ m];
    float sgn = (tid & m) ? -1.f : 1.f;
    re = fmaf(sgn, re, p.x) * RS;
    im = fmaf(sgn, im, p.y) * RS;
  }
#pragma unroll
  for (int w = 2; w < 8; ++w) {
    const int m = 1 << (7 - w);
    float pre = __shfl_xor(re, m);
    float pim = __shfl_xor(im, m);
    float sgn = (tid & m) ? -1.f : 1.f;
    re = fmaf(sgn, re, pre) * RS;
    im = fmaf(sgn, im, pim) * RS;
  }

  // 10 layers: 8 RX gates + diagonal (folded into wire-7 update)
  for (int layer = 0; layer < 10; ++layer) {
    const float* cs = &csl[16 * layer];
#pragma unroll
    for (int w = 0; w < 2; ++w) {
      const int m = 128 >> w;
      const float c = cs[2 * w], s = cs[2 * w + 1];
      cur ^= 1;
      buf[cur][tid] = make_float2(re, im);
      __syncthreads();
      float2 p = buf[cur][tid ^ m];
      float nre = fmaf(s, p.y, c * re);     // c*a - i*s*b
      float nim = fmaf(-s, p.x, c * im);
      re = nre; im = nim;
    }
#pragma unroll
    for (int w = 2; w < 8; ++w) {
      const int m = 1 << (7 - w);
      const float c = cs[2 * w], s = cs[2 * w + 1];
      float pre = __shfl_xor(re, m);
      float pim = __shfl_xor(im, m);
      float nre = fmaf(s, pim, c * re);
      float nim = fmaf(-s, pre, c * im);
      if (w == 7) {
        float tre = nre * dre - nim * dim_;
        nim = fmaf(nre, dim_, nim * dre);
        nre = tre;
      }
      re = nre; im = nim;
    }
  }

  // expvals of PauliZ on each wire
  const float prb = re * re + im * im;
#pragma unroll
  for (int w = 0; w < 8; ++w) {
    float v = ((tid >> (7 - w)) & 1) ? -prb : prb;
#pragma unroll
    for (int off = 32; off >= 1; off >>= 1) v += __shfl_xor(v, off);
    if (lane == 0) part[wid][w] = v;
  }
  __syncthreads();
  if (tid < 8) qv[tid] = part[0][tid] + part[1][tid] + part[2][tid] + part[3][tid];
  __syncthreads();

  // head: 8 -> 128 -> 64 -> 10
  if (tid < 128) {
    float a = p1b[tid];
#pragma unroll
    for (int k = 0; k < 8; ++k) a = fmaf(qv[k], p1w[tid * 8 + k], a);
    z1[tid] = fmaxf(a, 0.f);
  }
  __syncthreads();
  if (tid < 64) {
    float a = p2b[tid];
#pragma unroll 16
    for (int k = 0; k < 128; ++k) a = fmaf(z1[k], p2w[tid * 128 + k], a);
    z2s[tid] = fmaxf(a, 0.f);
  }
  __syncthreads();
  if (tid < 10) {
    float a = p3b[tid];
#pragma unroll 16
    for (int k = 0; k < 64; ++k) a = fmaf(z2s[k], p3w[tid * 64 + k], a);
    out[b * 10 + tid] = a;
  }
}

// ---------------------------------------------------------------------------
extern "C" void kernel_launch(void* const* d_in, const int* in_sizes, int n_in,
                              void* d_out, int out_size, void* d_ws, size_t ws_size,
                              hipStream_t stream) {
  (void)in_sizes; (void)n_in; (void)out_size; (void)ws_size;
  const float* x    = (const float*)d_in[0];
  const float* c1w  = (const float*)d_in[1];
  const float* c1b  = (const float*)d_in[2];
  const float* bn1g = (const float*)d_in[3];
  const float* bn1b = (const float*)d_in[4];
  const float* bn1m = (const float*)d_in[5];
  const float* bn1v = (const float*)d_in[6];
  const float* c2w  = (const float*)d_in[7];
  const float* c2b  = (const float*)d_in[8];
  const float* bn2g = (const float*)d_in[9];
  const float* bn2b = (const float*)d_in[10];
  const float* bn2m = (const float*)d_in[11];
  const float* bn2v = (const float*)d_in[12];
  const float* fc_w = (const float*)d_in[13];
  const float* fc_b = (const float*)d_in[14];
  const float* qp   = (const float*)d_in[15];
  const float* p1w  = (const float*)d_in[16];
  const float* p1b  = (const float*)d_in[17];
  const float* p2w  = (const float*)d_in[18];
  const float* p2b  = (const float*)d_in[19];
  const float* p3w  = (const float*)d_in[20];
  const float* p3b  = (const float*)d_in[21];
  float* ws = (float*)d_ws;
  float* outp = (float*)d_out;

  prep_kernel<<<3136, 256, 0, stream>>>(fc_w, c2w, c1w,
                                        bn1g, bn1b, bn1m, bn1v, c1b,
                                        bn2g, bn2b, bn2m, bn2v, c2b, ws);
  conv1_kernel<<<B_SZ, 256, 0, stream>>>(x, ws + OFF_W1T, ws + OFF_SC1, ws + OFF_SH1, ws + OFF_H1);
  conv2_kernel<<<B_SZ, 256, 0, stream>>>(ws + OFF_H1, ws + OFF_W2T, ws + OFF_SC2, ws + OFF_SH2, ws + OFF_H2P);
  // fc partials overwrite H1 (dead after conv2)
  fc_kernel<<<dim3(4, 32, KSPLIT), 256, 0, stream>>>(ws + OFF_H2P, ws + OFF_FCWP, ws + OFF_H1);
  quantum_kernel<<<B_SZ, 256, 0, stream>>>(ws + OFF_H1, fc_b, qp, p1w, p1b, p2w, p2b, p3w, p3b, outp);
}

// Round 4
// 195.495 us; speedup vs baseline: 1.7179x; 1.3632x over previous
//
#include <hip/hip_runtime.h>
#include <math.h>

// ---------------------------------------------------------------------------
// AmplitudeQuantumNet: conv1+bn+relu+pool -> conv2+bn+relu+pool -> fc+tanh ->
// 8-qubit statevector sim (H layer, 10x [RX x8 + S/T phase + CZ diag]) ->
// expvals -> 8->128->64->10 MLP head.
// R2: fc split-K x7, reduce folded into quantum; quantum shuffles for wires 2-7.
// R3: conv2 rewritten as MFMA implicit GEMM (split-bf16, fp32-accurate):
//     9 taps x K=32 16x16x32 MFMAs, A from LDS [y][x][ic] hi/lo, B fragments
//     pre-packed by prep. bn+relu+2x2 maxpool epilogue via LDS round-trip.
// ---------------------------------------------------------------------------

#define B_SZ 1024

// workspace offsets (in floats)
#define OFF_FCWP   0            // [3136][256] permuted fc_w
#define OFF_W2F    802816       // ushort[36864] conv2 B-fragments (bf16 hi/lo)
#define OFF_W1T    821248       // [9][32]     conv1 w transposed
#define OFF_SC1    821536       // [32]
#define OFF_SH1    821568       // [32]
#define OFF_SC2    821600      // [64]
#define OFF_SH2    821664      // [64]
#define OFF_H1     821728      // [1024][32][14][14]; reused as fc partials [7][1024][256]
#define OFF_H2P    7244256     // [1024][49][64]  (spatial-major, oc inner)

#define KSPLIT 7
#define KCHUNK 448              // 3136 / 7, = 14 * 32

typedef __attribute__((ext_vector_type(8))) short s16x8;
typedef __attribute__((ext_vector_type(4))) float f32x4;

__constant__ float C_COS8[8] = {1.f, 0.70710678f, 0.f, -0.70710678f, -1.f, -0.70710678f, 0.f, 0.70710678f};
__constant__ float C_SIN8[8] = {0.f, 0.70710678f, 1.f, 0.70710678f, 0.f, -0.70710678f, -1.f, -0.70710678f};

__device__ __forceinline__ unsigned short bf16_rne(float f) {
  unsigned u = __float_as_uint(f);
  unsigned r = u + 0x7FFFu + ((u >> 16) & 1u);
  return (unsigned short)(r >> 16);
}
__device__ __forceinline__ int div14(int m) {        // exact for 0 <= m <= 207
  return __float2int_rz((float)m * 0.07142858f);
}

// ------------------------- prep: transposes + bn folding -------------------
__global__ __launch_bounds__(256) void prep_kernel(
    const float* __restrict__ fc_w, const float* __restrict__ c2w, const float* __restrict__ c1w,
    const float* __restrict__ bn1g, const float* __restrict__ bn1b, const float* __restrict__ bn1m,
    const float* __restrict__ bn1v, const float* __restrict__ c1b,
    const float* __restrict__ bn2g, const float* __restrict__ bn2b, const float* __restrict__ bn2m,
    const float* __restrict__ bn2v, const float* __restrict__ c2b,
    float* __restrict__ ws) {
  int g = blockIdx.x * 256 + threadIdx.x;   // < 802816
  // fc_w permutation: k' = s*64 + oc  <->  original col = oc*49 + s
  int kp = g >> 8;          // [0,3136)
  int o  = g & 255;
  int s  = kp >> 6;         // [0,49)
  int oc = kp & 63;
  ws[OFF_FCWP + kp * 256 + o] = fc_w[o * 3136 + oc * 49 + s];

  if (g < 36864) {
    // conv2 B-fragments: g = ((w*9+t)*2+h)*512 + L*8 + j
    // lane L holds B^T[n=L&15][k=(L>>4)*8+j] for oc-tile w, tap t, part h
    int j = g & 7, L = (g >> 3) & 63, rest = g >> 9;
    int h = rest & 1; rest >>= 1;
    int t = rest % 9, w = rest / 9;
    int occ = w * 16 + (L & 15);
    int ic  = (L >> 4) * 8 + j;
    float v = c2w[occ * 288 + ic * 9 + t];
    unsigned short hi = bf16_rne(v);
    unsigned short res = hi;
    if (h) res = bf16_rne(v - __uint_as_float((unsigned)hi << 16));
    ((unsigned short*)(ws + OFF_W2F))[g] = res;
  }
  if (g < 288) {            // w1T[k*32+oc] = c1w[oc*9+k]
    ws[OFF_W1T + g] = c1w[(g & 31) * 9 + (g >> 5)];
  }
  if (g < 32) {
    float inv = bn1g[g] / sqrtf(bn1v[g] + 1e-5f);
    ws[OFF_SC1 + g] = inv;
    ws[OFF_SH1 + g] = c1b[g] * inv + bn1b[g] - bn1m[g] * inv;
  }
  if (g < 64) {
    float inv = bn2g[g] / sqrtf(bn2v[g] + 1e-5f);
    ws[OFF_SC2 + g] = inv;
    ws[OFF_SH2 + g] = c2b[g] * inv + bn2b[g] - bn2m[g] * inv;
  }
}

// ------------------------- conv1 + bn + relu + pool ------------------------
// in: x[b][28][28], out: h1[b][32][14][14] (NCHW)
__global__ __launch_bounds__(256) void conv1_kernel(
    const float* __restrict__ x, const float* __restrict__ w1T,
    const float* __restrict__ sc1, const float* __restrict__ sh1,
    float* __restrict__ h1) {
  const int b = blockIdx.x, tid = threadIdx.x;
  __shared__ float xs[30][32];     // padded 28x28, row stride 32
  __shared__ float w1s[288];
  __shared__ float sc1s[32], sh1s[32];

  float4* xsf = (float4*)&xs[0][0];
  if (tid < 240) xsf[tid] = make_float4(0.f, 0.f, 0.f, 0.f);
  __syncthreads();
  const float* xb = x + b * 784;
  for (int i = tid; i < 784; i += 256) {
    int y = i / 28, c = i - y * 28;
    xs[y + 1][c + 1] = xb[i];
  }
  for (int i = tid; i < 288; i += 256) w1s[i] = w1T[i];
  if (tid < 32) { sc1s[tid] = sc1[tid]; sh1s[tid] = sh1[tid]; }
  __syncthreads();

  for (int t = tid; t < 448; t += 256) {
    const int oc = t & 31, py = t >> 5;
    float wv[9];
#pragma unroll
    for (int k = 0; k < 9; ++k) wv[k] = w1s[k * 32 + oc];
    float acc0[28], acc1[28];
#pragma unroll
    for (int j = 0; j < 28; ++j) { acc0[j] = 0.f; acc1[j] = 0.f; }
#pragma unroll
    for (int r = 0; r < 4; ++r) {
      const int pr = 2 * py + r;
      float row[32];
#pragma unroll
      for (int q = 0; q < 8; ++q) {
        float4 v = *(const float4*)&xs[pr][4 * q];
        row[4 * q] = v.x; row[4 * q + 1] = v.y; row[4 * q + 2] = v.z; row[4 * q + 3] = v.w;
      }
      if (r <= 2) {
#pragma unroll
        for (int kx = 0; kx < 3; ++kx) {
          const float w = wv[r * 3 + kx];
#pragma unroll
          for (int xx = 0; xx < 28; ++xx) acc0[xx] = fmaf(row[xx + kx], w, acc0[xx]);
        }
      }
      if (r >= 1) {
#pragma unroll
        for (int kx = 0; kx < 3; ++kx) {
          const float w = wv[(r - 1) * 3 + kx];
#pragma unroll
          for (int xx = 0; xx < 28; ++xx) acc1[xx] = fmaf(row[xx + kx], w, acc1[xx]);
        }
      }
    }
    const float sc = sc1s[oc], sh = sh1s[oc];
    float* dst = h1 + b * 6272 + oc * 196 + py * 14;
#pragma unroll
    for (int px = 0; px < 14; ++px) {
      float v0 = fmaxf(fmaf(acc0[2 * px], sc, sh), 0.f);
      float v1 = fmaxf(fmaf(acc0[2 * px + 1], sc, sh), 0.f);
      float v2 = fmaxf(fmaf(acc1[2 * px], sc, sh), 0.f);
      float v3 = fmaxf(fmaf(acc1[2 * px + 1], sc, sh), 0.f);
      dst[px] = fmaxf(fmaxf(v0, v1), fmaxf(v2, v3));
    }
  }
}

// ------------------------- conv2: MFMA implicit GEMM -----------------------
// in: h1[b][32][14][14] fp32; out: h2p[b][49][64] (spatial-major, oc inner)
// M=196 conv outputs (13 tiles of 16), N=64 oc (wave w -> oc tile of 16),
// 9 taps x K=32, split-bf16 (3 MFMAs per product pair).
__global__ __launch_bounds__(256, 2) void conv2_kernel(
    const float* __restrict__ h1, const float* __restrict__ w2f_f,
    const float* __restrict__ sc2, const float* __restrict__ sh2,
    float* __restrict__ h2p) {
  const int b = blockIdx.x, tid = threadIdx.x;
  const int lane = tid & 63, w = tid >> 6;

  // LDS union. phase1: tile_hi/lo [17][16][32] bf16 (2 x 17408 B);
  //            phase2: conv_out per-wave [196][16] fp32 (4 x 12544 B)
  __shared__ unsigned char lds_raw[50176];
  unsigned short* tile_hi = (unsigned short*)lds_raw;
  unsigned short* tile_lo = (unsigned short*)(lds_raw + 17408);
  float* conv_out = (float*)lds_raw;

  // ---- B fragments: 9 taps x {hi,lo}, one dwordx4 each ----
  const unsigned short* w2f = (const unsigned short*)w2f_f;
  s16x8 bf[9][2];
#pragma unroll
  for (int t = 0; t < 9; ++t)
#pragma unroll
    for (int h = 0; h < 2; ++h)
      bf[t][h] = *(const s16x8*)&w2f[(((w * 9 + t) * 2 + h) << 9) + lane * 8];

  // ---- zero input tile (incl. padding) ----
  {
    float4* z = (float4*)lds_raw;
    for (int i = tid; i < 2176; i += 256) z[i] = make_float4(0.f, 0.f, 0.f, 0.f);
  }
  __syncthreads();

  // ---- stage h1 -> bf16 hi/lo, layout [y(17)][x(16)][ic(32)] ----
  if (tid < 196) {
    const int y = div14(tid), x = tid - y * 14;
    const int sp = ((y + 1) * 16 + (x + 1)) * 32;
    const float* src = h1 + b * 6272 + tid;
#pragma unroll
    for (int c = 0; c < 4; ++c) {
      s16x8 hv, lv;
#pragma unroll
      for (int j = 0; j < 8; ++j) {
        float v = src[(c * 8 + j) * 196];      // coalesced across lanes
        unsigned short h16 = bf16_rne(v);
        hv[j] = (short)h16;
        lv[j] = (short)bf16_rne(v - __uint_as_float((unsigned)h16 << 16));
      }
      *(s16x8*)&tile_hi[sp + c * 8] = hv;
      *(s16x8*)&tile_lo[sp + c * 8] = lv;
    }
  }
  __syncthreads();

  // ---- main MFMA loop ----
  f32x4 acc[13];
#pragma unroll
  for (int i = 0; i < 13; ++i) acc[i] = (f32x4){0.f, 0.f, 0.f, 0.f};

  const int kg8 = (lane >> 4) * 8;
#pragma unroll
  for (int mt = 0; mt < 13; ++mt) {
    const int m = mt * 16 + (lane & 15);
    const int y = div14(m), x = m - y * 14;
    const int base = (y * 16 + x) * 32 + kg8;
#pragma unroll
    for (int dy = 0; dy < 3; ++dy) {
#pragma unroll
      for (int dx = 0; dx < 3; ++dx) {
        const int off = base + (dy * 16 + dx) * 32;
        s16x8 ah = *(s16x8*)&tile_hi[off];
        s16x8 al = *(s16x8*)&tile_lo[off];
        const int t = dy * 3 + dx;
        acc[mt] = __builtin_amdgcn_mfma_f32_16x16x32_bf16(ah, bf[t][0], acc[mt], 0, 0, 0);
        acc[mt] = __builtin_amdgcn_mfma_f32_16x16x32_bf16(ah, bf[t][1], acc[mt], 0, 0, 0);
        acc[mt] = __builtin_amdgcn_mfma_f32_16x16x32_bf16(al, bf[t][0], acc[mt], 0, 0, 0);
      }
    }
  }
  __syncthreads();   // all tile reads done before conv_out overwrites LDS

  // ---- epilogue: bn+relu into per-wave LDS region ----
  const int oc = w * 16 + (lane & 15);
  const float sc = sc2[oc], sh = sh2[oc];
  float* cw = conv_out + w * 3136;   // 196*16 per wave
#pragma unroll
  for (int mt = 0; mt < 13; ++mt) {
#pragma unroll
    for (int r = 0; r < 4; ++r) {
      const int m = mt * 16 + (lane >> 4) * 4 + r;   // C/D: row=(lane>>4)*4+r, col=lane&15
      if (m < 196) cw[m * 16 + (lane & 15)] = fmaxf(fmaf(acc[mt][r], sc, sh), 0.f);
    }
  }
  __syncthreads();

  // ---- 2x2 maxpool + store [b][49][64] ----
#pragma unroll
  for (int i = 0; i < 13; ++i) {
    const int ps = i * 4 + (lane >> 4);
    if (ps < 49) {
      const int py = (ps * 37) >> 8, px = ps - py * 7;
      const int m00 = py * 28 + px * 2;
      const int c0 = m00 * 16 + (lane & 15);
      float v0 = cw[c0], v1 = cw[c0 + 16], v2 = cw[c0 + 224], v3 = cw[c0 + 240];
      h2p[b * 3136 + ps * 64 + oc] = fmaxf(fmaxf(v0, v1), fmaxf(v2, v3));
    }
  }
}

// ------------------------- fc (split-K partials) ----------------------------
// Part[z][1024][256] = A[1024][kz] @ Bp[kz][256] for k-slice z
__global__ __launch_bounds__(256) void fc_kernel(
    const float* __restrict__ A, const float* __restrict__ Bp,
    float* __restrict__ Part) {
  __shared__ float As[32][34];   // [k][m], transposed
  __shared__ float Bs[32][68];   // [k][n]
  const int tid = threadIdx.x;
  const int m0 = blockIdx.y * 32, n0 = blockIdx.x * 64;
  const int kbase = blockIdx.z * KCHUNK;
  const int am = tid >> 3, ak4 = tid & 7;
  const int bn4 = tid & 15, bk = tid >> 4;
  const int tx = tid & 15, ty = tid >> 4;
  float acc[2][4] = {{0.f, 0.f, 0.f, 0.f}, {0.f, 0.f, 0.f, 0.f}};
  for (int k0 = kbase; k0 < kbase + KCHUNK; k0 += 32) {
    float4 av  = *(const float4*)&A[(m0 + am) * 3136 + k0 + 4 * ak4];
    float4 bv0 = *(const float4*)&Bp[(k0 + bk) * 256 + n0 + 4 * bn4];
    float4 bv1 = *(const float4*)&Bp[(k0 + bk + 16) * 256 + n0 + 4 * bn4];
    As[4 * ak4 + 0][am] = av.x; As[4 * ak4 + 1][am] = av.y;
    As[4 * ak4 + 2][am] = av.z; As[4 * ak4 + 3][am] = av.w;
    *(float4*)&Bs[bk][4 * bn4] = bv0;
    *(float4*)&Bs[bk + 16][4 * bn4] = bv1;
    __syncthreads();
#pragma unroll
    for (int kk = 0; kk < 32; ++kk) {
      float2 a2 = *(const float2*)&As[kk][2 * ty];
      float4 b4 = *(const float4*)&Bs[kk][4 * tx];
      acc[0][0] = fmaf(a2.x, b4.x, acc[0][0]); acc[0][1] = fmaf(a2.x, b4.y, acc[0][1]);
      acc[0][2] = fmaf(a2.x, b4.z, acc[0][2]); acc[0][3] = fmaf(a2.x, b4.w, acc[0][3]);
      acc[1][0] = fmaf(a2.y, b4.x, acc[1][0]); acc[1][1] = fmaf(a2.y, b4.y, acc[1][1]);
      acc[1][2] = fmaf(a2.y, b4.z, acc[1][2]); acc[1][3] = fmaf(a2.y, b4.w, acc[1][3]);
    }
    __syncthreads();
  }
  float* dst = Part + blockIdx.z * 262144;
#pragma unroll
  for (int i = 0; i < 2; ++i) {
    const int m = m0 + 2 * ty + i;
    *(float4*)&dst[m * 256 + n0 + 4 * tx] =
        make_float4(acc[i][0], acc[i][1], acc[i][2], acc[i][3]);
  }
}

// ------------------------- quantum sim + MLP head --------------------------
// feats = tanh(sum_z Part[z][b][tid] + fc_b[tid]) computed inline.
__global__ __launch_bounds__(256) void quantum_kernel(
    const float* __restrict__ Part, const float* __restrict__ fc_b,
    const float* __restrict__ qp,
    const float* __restrict__ p1w, const float* __restrict__ p1b,
    const float* __restrict__ p2w, const float* __restrict__ p2b,
    const float* __restrict__ p3w, const float* __restrict__ p3b,
    float* __restrict__ out) {
  const int b = blockIdx.x, tid = threadIdx.x;
  __shared__ float2 buf[2][256];
  __shared__ float csl[160];       // cos/sin of q_params/2
  __shared__ float part[4][8];
  __shared__ float qv[8];
  __shared__ float z1[128];
  __shared__ float z2s[64];

  if (tid < 80) {
    float t = 0.5f * qp[tid];
    csl[2 * tid] = cosf(t);
    csl[2 * tid + 1] = sinf(t);
  }

  // fc partial-sum + bias + tanh (split-K reduce folded in)
  float f = fc_b[tid];
#pragma unroll
  for (int z = 0; z < KSPLIT; ++z) f += Part[z * 262144 + b * 256 + tid];
  f = tanhf(f);

  float ss = f * f;
#pragma unroll
  for (int off = 32; off >= 1; off >>= 1) ss += __shfl_xor(ss, off);
  const int lane = tid & 63, wid = tid >> 6;
  if (lane == 0) part[wid][0] = ss;
  __syncthreads();
  const float tot = part[0][0] + part[1][0] + part[2][0] + part[3][0];
  const float inv = 1.0f / sqrtf(tot);
  float re = f * inv, im = 0.f;

  // fixed diagonal for this basis state: S/T phases (even/odd wires) * CZ signs
  const int k8 = (2 * __popc(tid & 0xAA) + __popc(tid & 0x55)) & 7;
  float dre = C_COS8[k8], dim_ = C_SIN8[k8];
  {
    const int i = tid;
    int par = ((i >> 7) & (i >> 6)) ^ ((i >> 5) & (i >> 4)) ^ ((i >> 3) & (i >> 2)) ^ ((i >> 1) & i)
            ^ ((i >> 6) & (i >> 5)) ^ ((i >> 4) & (i >> 3)) ^ ((i >> 2) & (i >> 1));
    if (par & 1) { dre = -dre; dim_ = -dim_; }
  }

  int cur = 0;
  const float RS = 0.70710678118654752f;

  // Hadamard layer: wires 0,1 (m=128,64) cross-wave via LDS; wires 2-7 shuffles
#pragma unroll
  for (int w = 0; w < 2; ++w) {
    const int m = 128 >> w;
    cur ^= 1;
    buf[cur][tid] = make_float2(re, im);
    __syncthreads();
    float2 p = buf[cur][tid ^ m];
    float sgn = (tid & m) ? -1.f : 1.f;
    re = fmaf(sgn, re, p.x) * RS;
    im = fmaf(sgn, im, p.y) * RS;
  }
#pragma unroll
  for (int w = 2; w < 8; ++w) {
    const int m = 1 << (7 - w);
    float pre = __shfl_xor(re, m);
    float pim = __shfl_xor(im, m);
    float sgn = (tid & m) ? -1.f : 1.f;
    re = fmaf(sgn, re, pre) * RS;
    im = fmaf(sgn, im, pim) * RS;
  }

  // 10 layers: 8 RX gates + diagonal (folded into wire-7 update)
  for (int layer = 0; layer < 10; ++layer) {
    const float* cs = &csl[16 * layer];
#pragma unroll
    for (int w = 0; w < 2; ++w) {
      const int m = 128 >> w;
      const float c = cs[2 * w], s = cs[2 * w + 1];
      cur ^= 1;
      buf[cur][tid] = make_float2(re, im);
      __syncthreads();
      float2 p = buf[cur][tid ^ m];
      float nre = fmaf(s, p.y, c * re);     // c*a - i*s*b
      float nim = fmaf(-s, p.x, c * im);
      re = nre; im = nim;
    }
#pragma unroll
    for (int w = 2; w < 8; ++w) {
      const int m = 1 << (7 - w);
      const float c = cs[2 * w], s = cs[2 * w + 1];
      float pre = __shfl_xor(re, m);
      float pim = __shfl_xor(im, m);
      float nre = fmaf(s, pim, c * re);
      float nim = fmaf(-s, pre, c * im);
      if (w == 7) {
        float tre = nre * dre - nim * dim_;
        nim = fmaf(nre, dim_, nim * dre);
        nre = tre;
      }
      re = nre; im = nim;
    }
  }

  // expvals of PauliZ on each wire
  const float prb = re * re + im * im;
#pragma unroll
  for (int w = 0; w < 8; ++w) {
    float v = ((tid >> (7 - w)) & 1) ? -prb : prb;
#pragma unroll
    for (int off = 32; off >= 1; off >>= 1) v += __shfl_xor(v, off);
    if (lane == 0) part[wid][w] = v;
  }
  __syncthreads();
  if (tid < 8) qv[tid] = part[0][tid] + part[1][tid] + part[2][tid] + part[3][tid];
  __syncthreads();

  // head: 8 -> 128 -> 64 -> 10
  if (tid < 128) {
    float a = p1b[tid];
#pragma unroll
    for (int k = 0; k < 8; ++k) a = fmaf(qv[k], p1w[tid * 8 + k], a);
    z1[tid] = fmaxf(a, 0.f);
  }
  __syncthreads();
  if (tid < 64) {
    float a = p2b[tid];
#pragma unroll 16
    for (int k = 0; k < 128; ++k) a = fmaf(z1[k], p2w[tid * 128 + k], a);
    z2s[tid] = fmaxf(a, 0.f);
  }
  __syncthreads();
  if (tid < 10) {
    float a = p3b[tid];
#pragma unroll 16
    for (int k = 0; k < 64; ++k) a = fmaf(z2s[k], p3w[tid * 64 + k], a);
    out[b * 10 + tid] = a;
  }
}

// ---------------------------------------------------------------------------
extern "C" void kernel_launch(void* const* d_in, const int* in_sizes, int n_in,
                              void* d_out, int out_size, void* d_ws, size_t ws_size,
                              hipStream_t stream) {
  (void)in_sizes; (void)n_in; (void)out_size; (void)ws_size;
  const float* x    = (const float*)d_in[0];
  const float* c1w  = (const float*)d_in[1];
  const float* c1b  = (const float*)d_in[2];
  const float* bn1g = (const float*)d_in[3];
  const float* bn1b = (const float*)d_in[4];
  const float* bn1m = (const float*)d_in[5];
  const float* bn1v = (const float*)d_in[6];
  const float* c2w  = (const float*)d_in[7];
  const float* c2b  = (const float*)d_in[8];
  const float* bn2g = (const float*)d_in[9];
  const float* bn2b = (const float*)d_in[10];
  const float* bn2m = (const float*)d_in[11];
  const float* bn2v = (const float*)d_in[12];
  const float* fc_w = (const float*)d_in[13];
  const float* fc_b = (const float*)d_in[14];
  const float* qp   = (const float*)d_in[15];
  const float* p1w  = (const float*)d_in[16];
  const float* p1b  = (const float*)d_in[17];
  const float* p2w  = (const float*)d_in[18];
  const float* p2b  = (const float*)d_in[19];
  const float* p3w  = (const float*)d_in[20];
  const float* p3b  = (const float*)d_in[21];
  float* ws = (float*)d_ws;
  float* outp = (float*)d_out;

  prep_kernel<<<3136, 256, 0, stream>>>(fc_w, c2w, c1w,
                                        bn1g, bn1b, bn1m, bn1v, c1b,
                                        bn2g, bn2b, bn2m, bn2v, c2b, ws);
  conv1_kernel<<<B_SZ, 256, 0, stream>>>(x, ws + OFF_W1T, ws + OFF_SC1, ws + OFF_SH1, ws + OFF_H1);
  conv2_kernel<<<B_SZ, 256, 0, stream>>>(ws + OFF_H1, ws + OFF_W2F, ws + OFF_SC2, ws + OFF_SH2, ws + OFF_H2P);
  // fc partials overwrite H1 (dead after conv2)
  fc_kernel<<<dim3(4, 32, KSPLIT), 256, 0, stream>>>(ws + OFF_H2P, ws + OFF_FCWP, ws + OFF_H1);
  quantum_kernel<<<B_SZ, 256, 0, stream>>>(ws + OFF_H1, fc_b, qp, p1w, p1b, p2w, p2b, p3w, p3b, outp);
}

// Round 5
// 177.574 us; speedup vs baseline: 1.8913x; 1.1009x over previous
//
#include <hip/hip_runtime.h>
#include <math.h>

// ---------------------------------------------------------------------------
// AmplitudeQuantumNet: conv1+bn+relu+pool -> conv2+bn+relu+pool -> fc+tanh ->
// 8-qubit statevector sim (H layer, 10x [RX x8 + S/T phase + CZ diag]) ->
// expvals -> 8->128->64->10 MLP head.
// R2: fc split-K, reduce folded into quantum; quantum shuffles for wires 2-7.
// R3: conv2 as MFMA implicit GEMM (split-bf16, fp32-accurate).
// R4: fc as MFMA GEMM too: conv2 emits h2 as bf16 hi/lo, prep pre-packs fc_w
//     B-fragments (bf16 hi/lo), fc = 3-MFMA split-bf16 products, split-K x14.
// ---------------------------------------------------------------------------

#define B_SZ 1024

// workspace offsets (in floats)
#define OFF_FCWP   0            // ushort[1605632] fc_w B-fragments (bf16 hi/lo)
#define OFF_W2F    802816       // ushort[36864] conv2 B-fragments (bf16 hi/lo)
#define OFF_W1T    821248       // [9][32]     conv1 w transposed
#define OFF_SC1    821536       // [32]
#define OFF_SH1    821568       // [32]
#define OFF_SC2    821600      // [64]
#define OFF_SH2    821664      // [64]
#define OFF_H1     821728      // [1024][32][14][14]; reused as fc partials [14][1024][256]
#define OFF_H2P    7244256     // ushort h2hi[1024][3136] ++ h2lo[1024][3136]

#define KSPLIT_FC 14
#define KCHUNK_FC 224           // 3136 / 14, = 7 * 32

typedef __attribute__((ext_vector_type(8))) short s16x8;
typedef __attribute__((ext_vector_type(4))) float f32x4;

__constant__ float C_COS8[8] = {1.f, 0.70710678f, 0.f, -0.70710678f, -1.f, -0.70710678f, 0.f, 0.70710678f};
__constant__ float C_SIN8[8] = {0.f, 0.70710678f, 1.f, 0.70710678f, 0.f, -0.70710678f, -1.f, -0.70710678f};

__device__ __forceinline__ unsigned short bf16_rne(float f) {
  unsigned u = __float_as_uint(f);
  unsigned r = u + 0x7FFFu + ((u >> 16) & 1u);
  return (unsigned short)(r >> 16);
}
__device__ __forceinline__ int div14(int m) {        // exact for 0 <= m <= 207
  return __float2int_rz((float)m * 0.07142858f);
}

// ------------------------- prep: weight packing + bn folding ---------------
__global__ __launch_bounds__(256) void prep_kernel(
    const float* __restrict__ fc_w, const float* __restrict__ c2w, const float* __restrict__ c1w,
    const float* __restrict__ bn1g, const float* __restrict__ bn1b, const float* __restrict__ bn1m,
    const float* __restrict__ bn1v, const float* __restrict__ c1b,
    const float* __restrict__ bn2g, const float* __restrict__ bn2b, const float* __restrict__ bn2m,
    const float* __restrict__ bn2v, const float* __restrict__ c2b,
    float* __restrict__ ws) {
  int g = blockIdx.x * 256 + threadIdx.x;   // < 802816

  // fc_w B-fragments (bf16 hi/lo): layout [kg 98][nt 16][part 2][lane 64][j 8]
  // lane holds B[k = kg*32 + (lane>>4)*8 + j][n = nt*16 + (lane&15)]
  // A k-index maps to orig fc col: k = s*64+oc  ->  col = oc*49 + s
  {
    int j = g & 7, lane = (g >> 3) & 63, nt = (g >> 9) & 15, kg = g >> 13;
    int n = nt * 16 + (lane & 15);
    int k = kg * 32 + ((lane >> 4) & 3) * 8 + j;
    float v = fc_w[n * 3136 + (k & 63) * 49 + (k >> 6)];
    unsigned short hi = bf16_rne(v);
    unsigned short lo = bf16_rne(v - __uint_as_float((unsigned)hi << 16));
    unsigned short* us = (unsigned short*)ws;   // OFF_FCWP == 0
    int base = ((kg * 16 + nt) * 2) * 512 + lane * 8 + j;
    us[base] = hi;
    us[base + 512] = lo;
  }

  if (g < 36864) {
    // conv2 B-fragments: g = ((w*9+t)*2+h)*512 + L*8 + j
    int j = g & 7, L = (g >> 3) & 63, rest = g >> 9;
    int h = rest & 1; rest >>= 1;
    int t = rest % 9, w = rest / 9;
    int occ = w * 16 + (L & 15);
    int ic  = (L >> 4) * 8 + j;
    float v = c2w[occ * 288 + ic * 9 + t];
    unsigned short hi = bf16_rne(v);
    unsigned short res = hi;
    if (h) res = bf16_rne(v - __uint_as_float((unsigned)hi << 16));
    ((unsigned short*)(ws + OFF_W2F))[g] = res;
  }
  if (g < 288) {            // w1T[k*32+oc] = c1w[oc*9+k]
    ws[OFF_W1T + g] = c1w[(g & 31) * 9 + (g >> 5)];
  }
  if (g < 32) {
    float inv = bn1g[g] / sqrtf(bn1v[g] + 1e-5f);
    ws[OFF_SC1 + g] = inv;
    ws[OFF_SH1 + g] = c1b[g] * inv + bn1b[g] - bn1m[g] * inv;
  }
  if (g < 64) {
    float inv = bn2g[g] / sqrtf(bn2v[g] + 1e-5f);
    ws[OFF_SC2 + g] = inv;
    ws[OFF_SH2 + g] = c2b[g] * inv + bn2b[g] - bn2m[g] * inv;
  }
}

// ------------------------- conv1 + bn + relu + pool ------------------------
// in: x[b][28][28], out: h1[b][32][14][14] (NCHW)
__global__ __launch_bounds__(256) void conv1_kernel(
    const float* __restrict__ x, const float* __restrict__ w1T,
    const float* __restrict__ sc1, const float* __restrict__ sh1,
    float* __restrict__ h1) {
  const int b = blockIdx.x, tid = threadIdx.x;
  __shared__ float xs[30][32];     // padded 28x28, row stride 32
  __shared__ float w1s[288];
  __shared__ float sc1s[32], sh1s[32];

  float4* xsf = (float4*)&xs[0][0];
  if (tid < 240) xsf[tid] = make_float4(0.f, 0.f, 0.f, 0.f);
  __syncthreads();
  const float* xb = x + b * 784;
  for (int i = tid; i < 784; i += 256) {
    int y = i / 28, c = i - y * 28;
    xs[y + 1][c + 1] = xb[i];
  }
  for (int i = tid; i < 288; i += 256) w1s[i] = w1T[i];
  if (tid < 32) { sc1s[tid] = sc1[tid]; sh1s[tid] = sh1[tid]; }
  __syncthreads();

  for (int t = tid; t < 448; t += 256) {
    const int oc = t & 31, py = t >> 5;
    float wv[9];
#pragma unroll
    for (int k = 0; k < 9; ++k) wv[k] = w1s[k * 32 + oc];
    float acc0[28], acc1[28];
#pragma unroll
    for (int j = 0; j < 28; ++j) { acc0[j] = 0.f; acc1[j] = 0.f; }
#pragma unroll
    for (int r = 0; r < 4; ++r) {
      const int pr = 2 * py + r;
      float row[32];
#pragma unroll
      for (int q = 0; q < 8; ++q) {
        float4 v = *(const float4*)&xs[pr][4 * q];
        row[4 * q] = v.x; row[4 * q + 1] = v.y; row[4 * q + 2] = v.z; row[4 * q + 3] = v.w;
      }
      if (r <= 2) {
#pragma unroll
        for (int kx = 0; kx < 3; ++kx) {
          const float w = wv[r * 3 + kx];
#pragma unroll
          for (int xx = 0; xx < 28; ++xx) acc0[xx] = fmaf(row[xx + kx], w, acc0[xx]);
        }
      }
      if (r >= 1) {
#pragma unroll
        for (int kx = 0; kx < 3; ++kx) {
          const float w = wv[(r - 1) * 3 + kx];
#pragma unroll
          for (int xx = 0; xx < 28; ++xx) acc1[xx] = fmaf(row[xx + kx], w, acc1[xx]);
        }
      }
    }
    const float sc = sc1s[oc], sh = sh1s[oc];
    float* dst = h1 + b * 6272 + oc * 196 + py * 14;
#pragma unroll
    for (int px = 0; px < 14; ++px) {
      float v0 = fmaxf(fmaf(acc0[2 * px], sc, sh), 0.f);
      float v1 = fmaxf(fmaf(acc0[2 * px + 1], sc, sh), 0.f);
      float v2 = fmaxf(fmaf(acc1[2 * px], sc, sh), 0.f);
      float v3 = fmaxf(fmaf(acc1[2 * px + 1], sc, sh), 0.f);
      dst[px] = fmaxf(fmaxf(v0, v1), fmaxf(v2, v3));
    }
  }
}

// ------------------------- conv2: MFMA implicit GEMM -----------------------
// in: h1[b][32][14][14] fp32; out: h2hi/h2lo[b][49][64] bf16 hi/lo
__global__ __launch_bounds__(256, 2) void conv2_kernel(
    const float* __restrict__ h1, const float* __restrict__ w2f_f,
    const float* __restrict__ sc2, const float* __restrict__ sh2,
    unsigned short* __restrict__ h2hi, unsigned short* __restrict__ h2lo) {
  const int b = blockIdx.x, tid = threadIdx.x;
  const int lane = tid & 63, w = tid >> 6;

  // LDS union. phase1: tile_hi/lo [17][16][32] bf16 (2 x 17408 B);
  //            phase2: conv_out per-wave [196][16] fp32 (4 x 12544 B)
  __shared__ unsigned char lds_raw[50176];
  unsigned short* tile_hi = (unsigned short*)lds_raw;
  unsigned short* tile_lo = (unsigned short*)(lds_raw + 17408);
  float* conv_out = (float*)lds_raw;

  // ---- B fragments: 9 taps x {hi,lo}, one dwordx4 each ----
  const unsigned short* w2f = (const unsigned short*)w2f_f;
  s16x8 bf[9][2];
#pragma unroll
  for (int t = 0; t < 9; ++t)
#pragma unroll
    for (int h = 0; h < 2; ++h)
      bf[t][h] = *(const s16x8*)&w2f[(((w * 9 + t) * 2 + h) << 9) + lane * 8];

  // ---- zero input tile (incl. padding) ----
  {
    float4* z = (float4*)lds_raw;
    for (int i = tid; i < 2176; i += 256) z[i] = make_float4(0.f, 0.f, 0.f, 0.f);
  }
  __syncthreads();

  // ---- stage h1 -> bf16 hi/lo, layout [y(17)][x(16)][ic(32)] ----
  if (tid < 196) {
    const int y = div14(tid), x = tid - y * 14;
    const int sp = ((y + 1) * 16 + (x + 1)) * 32;
    const float* src = h1 + b * 6272 + tid;
#pragma unroll
    for (int c = 0; c < 4; ++c) {
      s16x8 hv, lv;
#pragma unroll
      for (int j = 0; j < 8; ++j) {
        float v = src[(c * 8 + j) * 196];      // coalesced across lanes
        unsigned short h16 = bf16_rne(v);
        hv[j] = (short)h16;
        lv[j] = (short)bf16_rne(v - __uint_as_float((unsigned)h16 << 16));
      }
      *(s16x8*)&tile_hi[sp + c * 8] = hv;
      *(s16x8*)&tile_lo[sp + c * 8] = lv;
    }
  }
  __syncthreads();

  // ---- main MFMA loop ----
  f32x4 acc[13];
#pragma unroll
  for (int i = 0; i < 13; ++i) acc[i] = (f32x4){0.f, 0.f, 0.f, 0.f};

  const int kg8 = (lane >> 4) * 8;
#pragma unroll
  for (int mt = 0; mt < 13; ++mt) {
    const int m = mt * 16 + (lane & 15);
    const int y = div14(m), x = m - y * 14;
    const int base = (y * 16 + x) * 32 + kg8;
#pragma unroll
    for (int dy = 0; dy < 3; ++dy) {
#pragma unroll
      for (int dx = 0; dx < 3; ++dx) {
        const int off = base + (dy * 16 + dx) * 32;
        s16x8 ah = *(s16x8*)&tile_hi[off];
        s16x8 al = *(s16x8*)&tile_lo[off];
        const int t = dy * 3 + dx;
        acc[mt] = __builtin_amdgcn_mfma_f32_16x16x32_bf16(ah, bf[t][0], acc[mt], 0, 0, 0);
        acc[mt] = __builtin_amdgcn_mfma_f32_16x16x32_bf16(ah, bf[t][1], acc[mt], 0, 0, 0);
        acc[mt] = __builtin_amdgcn_mfma_f32_16x16x32_bf16(al, bf[t][0], acc[mt], 0, 0, 0);
      }
    }
  }
  __syncthreads();   // all tile reads done before conv_out overwrites LDS

  // ---- epilogue: bn+relu into per-wave LDS region ----
  const int oc = w * 16 + (lane & 15);
  const float sc = sc2[oc], sh = sh2[oc];
  float* cw = conv_out + w * 3136;   // 196*16 per wave
#pragma unroll
  for (int mt = 0; mt < 13; ++mt) {
#pragma unroll
    for (int r = 0; r < 4; ++r) {
      const int m = mt * 16 + (lane >> 4) * 4 + r;   // C/D: row=(lane>>4)*4+r, col=lane&15
      if (m < 196) cw[m * 16 + (lane & 15)] = fmaxf(fmaf(acc[mt][r], sc, sh), 0.f);
    }
  }
  __syncthreads();

  // ---- 2x2 maxpool + bf16 hi/lo store [b][49][64] ----
#pragma unroll
  for (int i = 0; i < 13; ++i) {
    const int ps = i * 4 + (lane >> 4);
    if (ps < 49) {
      const int py = (ps * 37) >> 8, px = ps - py * 7;
      const int m00 = py * 28 + px * 2;
      const int c0 = m00 * 16 + (lane & 15);
      float v0 = cw[c0], v1 = cw[c0 + 16], v2 = cw[c0 + 224], v3 = cw[c0 + 240];
      float vm = fmaxf(fmaxf(v0, v1), fmaxf(v2, v3));
      unsigned short hv = bf16_rne(vm);
      const int idx = b * 3136 + ps * 64 + oc;
      h2hi[idx] = hv;
      h2lo[idx] = bf16_rne(vm - __uint_as_float((unsigned)hv << 16));
    }
  }
}

// ------------------------- fc: MFMA GEMM (split-bf16, split-K) --------------
// Part[z][1024][256] = A[1024][kz] @ B[kz][256]; A = h2 bf16 hi/lo,
// B = pre-packed fc_w fragments. Block: M=64 (1 m-frag/wave), N=128, 7 chunks.
__global__ __launch_bounds__(256) void fc_mfma_kernel(
    const unsigned short* __restrict__ h2hi, const unsigned short* __restrict__ h2lo,
    const unsigned short* __restrict__ Bfrag, float* __restrict__ Part) {
  __shared__ unsigned short Bs[8192];   // 16 KB: [nf 8][part 2][lane 64][j 8]
  const int tid = threadIdx.x;
  const int lane = tid & 63, w = tid >> 6;
  const int m0 = blockIdx.y * 64, nt0 = blockIdx.x * 8, z = blockIdx.z;
  const int kz = z * KCHUNK_FC;

  const int mrow = m0 + w * 16 + (lane & 15);
  const int kg8 = (lane >> 4) * 8;
  const unsigned short* arow_hi = h2hi + mrow * 3136;
  const unsigned short* arow_lo = h2lo + mrow * 3136;

  f32x4 acc[8];
#pragma unroll
  for (int i = 0; i < 8; ++i) acc[i] = (f32x4){0.f, 0.f, 0.f, 0.f};

  for (int c = 0; c < 7; ++c) {
    const int kg = (kz >> 5) + c;
    // stage B chunk: 16 KB contiguous ([kg][nt0..nt0+7][2][512])
    {
      const uint4* src = (const uint4*)(Bfrag + (size_t)(kg * 16 + nt0) * 1024);
      uint4* dst = (uint4*)Bs;
#pragma unroll
      for (int i = 0; i < 4; ++i) dst[tid + 256 * i] = src[tid + 256 * i];
    }
    __syncthreads();

    const int k0 = kz + c * 32;
    s16x8 ah = *(const s16x8*)(arow_hi + k0 + kg8);
    s16x8 al = *(const s16x8*)(arow_lo + k0 + kg8);
#pragma unroll
    for (int nf = 0; nf < 8; ++nf) {
      s16x8 bh = *(s16x8*)&Bs[(nf * 2 + 0) * 512 + lane * 8];
      s16x8 bl = *(s16x8*)&Bs[(nf * 2 + 1) * 512 + lane * 8];
      acc[nf] = __builtin_amdgcn_mfma_f32_16x16x32_bf16(ah, bh, acc[nf], 0, 0, 0);
      acc[nf] = __builtin_amdgcn_mfma_f32_16x16x32_bf16(ah, bl, acc[nf], 0, 0, 0);
      acc[nf] = __builtin_amdgcn_mfma_f32_16x16x32_bf16(al, bh, acc[nf], 0, 0, 0);
    }
    __syncthreads();
  }

  float* dst = Part + (size_t)z * 262144;
  const int mbase = m0 + w * 16 + (lane >> 4) * 4;
  const int nbase = nt0 * 16 + (lane & 15);
#pragma unroll
  for (int nf = 0; nf < 8; ++nf) {
#pragma unroll
    for (int r = 0; r < 4; ++r) {
      dst[(mbase + r) * 256 + nbase + nf * 16] = acc[nf][r];
    }
  }
}

// ------------------------- quantum sim + MLP head --------------------------
// feats = tanh(sum_z Part[z][b][tid] + fc_b[tid]) computed inline.
__global__ __launch_bounds__(256) void quantum_kernel(
    const float* __restrict__ Part, const float* __restrict__ fc_b,
    const float* __restrict__ qp,
    const float* __restrict__ p1w, const float* __restrict__ p1b,
    const float* __restrict__ p2w, const float* __restrict__ p2b,
    const float* __restrict__ p3w, const float* __restrict__ p3b,
    float* __restrict__ out) {
  const int b = blockIdx.x, tid = threadIdx.x;
  __shared__ float2 buf[2][256];
  __shared__ float csl[160];       // cos/sin of q_params/2
  __shared__ float part[4][8];
  __shared__ float qv[8];
  __shared__ float z1[128];
  __shared__ float z2s[64];

  if (tid < 80) {
    float t = 0.5f * qp[tid];
    csl[2 * tid] = cosf(t);
    csl[2 * tid + 1] = sinf(t);
  }

  // fc partial-sum + bias + tanh (split-K reduce folded in)
  float f = fc_b[tid];
#pragma unroll
  for (int z = 0; z < KSPLIT_FC; ++z) f += Part[z * 262144 + b * 256 + tid];
  f = tanhf(f);

  float ss = f * f;
#pragma unroll
  for (int off = 32; off >= 1; off >>= 1) ss += __shfl_xor(ss, off);
  const int lane = tid & 63, wid = tid >> 6;
  if (lane == 0) part[wid][0] = ss;
  __syncthreads();
  const float tot = part[0][0] + part[1][0] + part[2][0] + part[3][0];
  const float inv = 1.0f / sqrtf(tot);
  float re = f * inv, im = 0.f;

  // fixed diagonal for this basis state: S/T phases (even/odd wires) * CZ signs
  const int k8 = (2 * __popc(tid & 0xAA) + __popc(tid & 0x55)) & 7;
  float dre = C_COS8[k8], dim_ = C_SIN8[k8];
  {
    const int i = tid;
    int par = ((i >> 7) & (i >> 6)) ^ ((i >> 5) & (i >> 4)) ^ ((i >> 3) & (i >> 2)) ^ ((i >> 1) & i)
            ^ ((i >> 6) & (i >> 5)) ^ ((i >> 4) & (i >> 3)) ^ ((i >> 2) & (i >> 1));
    if (par & 1) { dre = -dre; dim_ = -dim_; }
  }

  int cur = 0;
  const float RS = 0.70710678118654752f;

  // Hadamard layer: wires 0,1 (m=128,64) cross-wave via LDS; wires 2-7 shuffles
#pragma unroll
  for (int w = 0; w < 2; ++w) {
    const int m = 128 >> w;
    cur ^= 1;
    buf[cur][tid] = make_float2(re, im);
    __syncthreads();
    float2 p = buf[cur][tid ^ m];
    float sgn = (tid & m) ? -1.f : 1.f;
    re = fmaf(sgn, re, p.x) * RS;
    im = fmaf(sgn, im, p.y) * RS;
  }
#pragma unroll
  for (int w = 2; w < 8; ++w) {
    const int m = 1 << (7 - w);
    float pre = __shfl_xor(re, m);
    float pim = __shfl_xor(im, m);
    float sgn = (tid & m) ? -1.f : 1.f;
    re = fmaf(sgn, re, pre) * RS;
    im = fmaf(sgn, im, pim) * RS;
  }

  // 10 layers: 8 RX gates + diagonal (folded into wire-7 update)
  for (int layer = 0; layer < 10; ++layer) {
    const float* cs = &csl[16 * layer];
#pragma unroll
    for (int w = 0; w < 2; ++w) {
      const int m = 128 >> w;
      const float c = cs[2 * w], s = cs[2 * w + 1];
      cur ^= 1;
      buf[cur][tid] = make_float2(re, im);
      __syncthreads();
      float2 p = buf[cur][tid ^ m];
      float nre = fmaf(s, p.y, c * re);     // c*a - i*s*b
      float nim = fmaf(-s, p.x, c * im);
      re = nre; im = nim;
    }
#pragma unroll
    for (int w = 2; w < 8; ++w) {
      const int m = 1 << (7 - w);
      const float c = cs[2 * w], s = cs[2 * w + 1];
      float pre = __shfl_xor(re, m);
      float pim = __shfl_xor(im, m);
      float nre = fmaf(s, pim, c * re);
      float nim = fmaf(-s, pre, c * im);
      if (w == 7) {
        float tre = nre * dre - nim * dim_;
        nim = fmaf(nre, dim_, nim * dre);
        nre = tre;
      }
      re = nre; im = nim;
    }
  }

  // expvals of PauliZ on each wire
  const float prb = re * re + im * im;
#pragma unroll
  for (int w = 0; w < 8; ++w) {
    float v = ((tid >> (7 - w)) & 1) ? -prb : prb;
#pragma unroll
    for (int off = 32; off >= 1; off >>= 1) v += __shfl_xor(v, off);
    if (lane == 0) part[wid][w] = v;
  }
  __syncthreads();
  if (tid < 8) qv[tid] = part[0][tid] + part[1][tid] + part[2][tid] + part[3][tid];
  __syncthreads();

  // head: 8 -> 128 -> 64 -> 10
  if (tid < 128) {
    float a = p1b[tid];
#pragma unroll
    for (int k = 0; k < 8; ++k) a = fmaf(qv[k], p1w[tid * 8 + k], a);
    z1[tid] = fmaxf(a, 0.f);
  }
  __syncthreads();
  if (tid < 64) {
    float a = p2b[tid];
#pragma unroll 16
    for (int k = 0; k < 128; ++k) a = fmaf(z1[k], p2w[tid * 128 + k], a);
    z2s[tid] = fmaxf(a, 0.f);
  }
  __syncthreads();
  if (tid < 10) {
    float a = p3b[tid];
#pragma unroll 16
    for (int k = 0; k < 64; ++k) a = fmaf(z2s[k], p3w[tid * 64 + k], a);
    out[b * 10 + tid] = a;
  }
}

// ---------------------------------------------------------------------------
extern "C" void kernel_launch(void* const* d_in, const int* in_sizes, int n_in,
                              void* d_out, int out_size, void* d_ws, size_t ws_size,
                              hipStream_t stream) {
  (void)in_sizes; (void)n_in; (void)out_size; (void)ws_size;
  const float* x    = (const float*)d_in[0];
  const float* c1w  = (const float*)d_in[1];
  const float* c1b  = (const float*)d_in[2];
  const float* bn1g = (const float*)d_in[3];
  const float* bn1b = (const float*)d_in[4];
  const float* bn1m = (const float*)d_in[5];
  const float* bn1v = (const float*)d_in[6];
  const float* c2w  = (const float*)d_in[7];
  const float* c2b  = (const float*)d_in[8];
  const float* bn2g = (const float*)d_in[9];
  const float* bn2b = (const float*)d_in[10];
  const float* bn2m = (const float*)d_in[11];
  const float* bn2v = (const float*)d_in[12];
  const float* fc_w = (const float*)d_in[13];
  const float* fc_b = (const float*)d_in[14];
  const float* qp   = (const float*)d_in[15];
  const float* p1w  = (const float*)d_in[16];
  const float* p1b  = (const float*)d_in[17];
  const float* p2w  = (const float*)d_in[18];
  const float* p2b  = (const float*)d_in[19];
  const float* p3w  = (const float*)d_in[20];
  const float* p3b  = (const float*)d_in[21];
  float* ws = (float*)d_ws;
  float* outp = (float*)d_out;

  unsigned short* h2hi = (unsigned short*)(ws + OFF_H2P);
  unsigned short* h2lo = h2hi + 3211264;
  const unsigned short* bfrag = (const unsigned short*)ws;   // OFF_FCWP == 0

  prep_kernel<<<3136, 256, 0, stream>>>(fc_w, c2w, c1w,
                                        bn1g, bn1b, bn1m, bn1v, c1b,
                                        bn2g, bn2b, bn2m, bn2v, c2b, ws);
  conv1_kernel<<<B_SZ, 256, 0, stream>>>(x, ws + OFF_W1T, ws + OFF_SC1, ws + OFF_SH1, ws + OFF_H1);
  conv2_kernel<<<B_SZ, 256, 0, stream>>>(ws + OFF_H1, ws + OFF_W2F, ws + OFF_SC2, ws + OFF_SH2,
                                         h2hi, h2lo);
  // fc partials overwrite H1 (dead after conv2)
  fc_mfma_kernel<<<dim3(2, 16, KSPLIT_FC), 256, 0, stream>>>(h2hi, h2lo, bfrag, ws + OFF_H1);
  quantum_kernel<<<B_SZ, 256, 0, stream>>>(ws + OFF_H1, fc_b, qp, p1w, p1b, p2w, p2b, p3w, p3b, outp);
}